// Round 7
// baseline (4812.062 us; speedup 1.0000x reference)
//
#include <hip/hip_runtime.h>
#include <stdint.h>

#define NPTS 400000
#define NVOX 281600
#define TPB  256
#define NBLK ((NPTS + TPB - 1) / TPB)
#define OUTN (NVOX * 128)

// XLA-style binning: division by constant folded to multiply-by-reciprocal
// in f32 (1/0.2f == 5.0f exactly, 1/4.0f == 0.25f exactly).
__device__ __forceinline__ int bin3(const float* __restrict__ pt,
                                    int& bx, int& by, int& bz) {
  float x = pt[1], y = pt[2], z = pt[3];
  bx = (int)fminf(fmaxf(floorf(x * 5.0f), 0.f), 351.f);
  by = (int)fminf(fmaxf(floorf((y + 40.f) * 5.0f), 0.f), 399.f);
  bz = (int)fminf(fmaxf(floorf((z + 3.f) * 0.25f), 0.f), 0.f);
  return (((int)pt[0] + bz) * 400 + by) * 352 + bx;
}

__device__ __forceinline__ int mkfeat(const float* __restrict__ pt,
    const float* __restrict__ vcnt, const float* __restrict__ vsx,
    const float* __restrict__ vsy, const float* __restrict__ vsz,
    float* f) {
  int bx, by, bz;
  int v = bin3(pt, bx, by, bz);
  float x = pt[1], y = pt[2], z = pt[3];
  float n = fmaxf(vcnt[v], 1.f);
  f[0] = x;  f[1] = y;  f[2] = z;  f[3] = pt[4];
  f[4] = x - vsx[v] / n;
  f[5] = y - vsy[v] / n;
  f[6] = z - vsz[v] / n;
  f[7] = x - (0.2f * (float)bx + 0.1f);
  f[8] = y - (0.2f * (float)by - 39.9f);
  f[9] = z - (4.0f * (float)bz - 1.0f);
  return v;
}

__device__ __forceinline__ float h0c(const float* f,
                                     const float* __restrict__ W0, int c) {
  float h = f[0] * W0[c];
  #pragma unroll
  for (int i = 1; i < 10; ++i) h = fmaf(f[i], W0[i * 64 + c], h);
  return h;
}

__global__ __launch_bounds__(256) void voxsum(const float* __restrict__ pts,
    float* __restrict__ vcnt, float* __restrict__ vsx,
    float* __restrict__ vsy, float* __restrict__ vsz) {
  int p = blockIdx.x * TPB + threadIdx.x;
  if (p >= NPTS) return;
  const float* pt = pts + (size_t)p * 5;
  int bx, by, bz;
  int v = bin3(pt, bx, by, bz);
  atomicAdd(&vcnt[v], 1.f);
  atomicAdd(&vsx[v], pt[1]);
  atomicAdd(&vsy[v], pt[2]);
  atomicAdd(&vsz[v], pt[3]);
}

__global__ __launch_bounds__(256) void bn0stats(const float* __restrict__ pts,
    const float* __restrict__ vcnt, const float* __restrict__ vsx,
    const float* __restrict__ vsy, const float* __restrict__ vsz,
    const float* __restrict__ W0,
    double* __restrict__ gs, double* __restrict__ gq) {
  __shared__ float bs[4][64], bq[4][64];
  int t = threadIdx.x, wv = t >> 6, ln = t & 63;
  int p = blockIdx.x * TPB + t;
  bool ok = p < NPTS;
  const float* pt = pts + (size_t)(ok ? p : 0) * 5;
  float f[10];
  mkfeat(pt, vcnt, vsx, vsy, vsz, f);
  for (int c = 0; c < 64; ++c) {
    float h = ok ? h0c(f, W0, c) : 0.f;
    float q = h * h;
    #pragma unroll
    for (int m = 1; m < 64; m <<= 1) {
      h += __shfl_xor(h, m, 64);
      q += __shfl_xor(q, m, 64);
    }
    if (ln == 0) { bs[wv][c] = h; bq[wv][c] = q; }
  }
  __syncthreads();
  if (t < 64) {
    atomicAdd(&gs[t], (double)bs[0][t] + bs[1][t] + bs[2][t] + bs[3][t]);
    atomicAdd(&gq[t], (double)bq[0][t] + bq[1][t] + bq[2][t] + bq[3][t]);
  }
}

__global__ void bnfold(const double* __restrict__ gs, const double* __restrict__ gq,
                       const float* __restrict__ gam, const float* __restrict__ bet,
                       float* __restrict__ sc, float* __restrict__ sh, int C) {
  int c = threadIdx.x;
  if (c >= C) return;
  double mu  = gs[c] / (double)NPTS;
  double var = gq[c] / (double)NPTS - mu * mu;
  double s = (double)gam[c] / sqrt(var + 1e-3);
  sc[c] = (float)s;
  sh[c] = (float)((double)bet[c] - mu * s);
}

__global__ __launch_bounds__(256) void pf0max(const float* __restrict__ pts,
    const float* __restrict__ vcnt, const float* __restrict__ vsx,
    const float* __restrict__ vsy, const float* __restrict__ vsz,
    const float* __restrict__ W0, const float* __restrict__ sc0,
    const float* __restrict__ sh0, unsigned int* __restrict__ vmax) {
  int p = blockIdx.x * TPB + threadIdx.x;
  if (p >= NPTS) return;
  const float* pt = pts + (size_t)p * 5;
  float f[10];
  int v = mkfeat(pt, vcnt, vsx, vsy, vsz, f);
  unsigned int* row = vmax + (size_t)v * 64;
  for (int c = 0; c < 64; ++c) {
    float pf = fmaxf(fmaf(h0c(f, W0, c), sc0[c], sh0[c]), 0.f);
    atomicMax(&row[c], __float_as_uint(pf));
  }
}

template <int STATS, int CB>
__global__ __launch_bounds__(256, 1) void layer1(const float* __restrict__ pts,
    const float* __restrict__ vcnt, const float* __restrict__ vsx,
    const float* __restrict__ vsy, const float* __restrict__ vsz,
    const float* __restrict__ W0, const float* __restrict__ sc0,
    const float* __restrict__ sh0, const unsigned int* __restrict__ vmax,
    const float* __restrict__ W1,
    double* __restrict__ gs, double* __restrict__ gq,
    const float* __restrict__ sc1, const float* __restrict__ sh1,
    unsigned int* __restrict__ outp) {
  __shared__ float bs[4][64], bq[4][64];
  int t = threadIdx.x, wv = t >> 6, ln = t & 63;
  int p = blockIdx.x * TPB + t;
  bool ok = p < NPTS;
  const float* pt = pts + (size_t)(ok ? p : 0) * 5;
  float f[10];
  int v = mkfeat(pt, vcnt, vsx, vsy, vsz, f);

  float acc[64];
  #pragma unroll
  for (int c = 0; c < 64; ++c) acc[c] = 0.f;

  for (int k = 0; k < 64; ++k) {
    float pf = fmaxf(fmaf(h0c(f, W0, k), sc0[k], sh0[k]), 0.f);
    const float* wr = W1 + (size_t)k * 128 + CB;
    #pragma unroll
    for (int c = 0; c < 64; ++c) acc[c] = fmaf(pf, wr[c], acc[c]);
  }
  const unsigned int* row = vmax + (size_t)v * 64;
  for (int k = 0; k < 64; ++k) {
    float pf = __uint_as_float(row[k]);
    const float* wr = W1 + (size_t)(64 + k) * 128 + CB;
    #pragma unroll
    for (int c = 0; c < 64; ++c) acc[c] = fmaf(pf, wr[c], acc[c]);
  }

  if (STATS) {
    for (int c = 0; c < 64; ++c) {
      float h = ok ? acc[c] : 0.f;
      float q = h * h;
      #pragma unroll
      for (int m = 1; m < 64; m <<= 1) {
        h += __shfl_xor(h, m, 64);
        q += __shfl_xor(q, m, 64);
      }
      if (ln == 0) { bs[wv][c] = h; bq[wv][c] = q; }
    }
    __syncthreads();
    if (t < 64) {
      atomicAdd(&gs[CB + t], (double)bs[0][t] + bs[1][t] + bs[2][t] + bs[3][t]);
      atomicAdd(&gq[CB + t], (double)bq[0][t] + bq[1][t] + bq[2][t] + bq[3][t]);
    }
  } else if (ok) {
    unsigned int* orow = outp + (size_t)v * 128 + CB;
    for (int c = 0; c < 64; ++c) {
      float val = fmaxf(fmaf(acc[c], sc1[CB + c], sh1[CB + c]), 0.f);
      atomicMax(&orow[c], __float_as_uint(val));   // val >= 0
    }
  }
}

extern "C" void kernel_launch(void* const* d_in, const int* in_sizes, int n_in,
                              void* d_out, int out_size, void* d_ws, size_t ws_size,
                              hipStream_t stream) {
  const float* pts = (const float*)d_in[0];
  const float* W0  = (const float*)d_in[1];
  const float* g0  = (const float*)d_in[2];
  const float* b0  = (const float*)d_in[3];
  const float* W1  = (const float*)d_in[4];
  const float* g1  = (const float*)d_in[5];
  const float* b1  = (const float*)d_in[6];

  char* base = (char*)d_ws;
  double* stats = (double*)base;              // 384 f64
  float*  fold  = (float*)(base + 3072);      // 384 f32
  float*  vcnt  = (float*)(base + 4608);
  float*  vsx   = vcnt + NVOX;
  float*  vsy   = vsx + NVOX;
  float*  vsz   = vsy + NVOX;
  unsigned int* vmax = (unsigned int*)(vsz + NVOX);  // NVOX*64 u32 (72 MB)
  double* s0 = stats,       *q0 = stats + 64;
  double* s1 = stats + 128, *q1 = stats + 256;
  float* sc0 = fold,       *sh0 = fold + 64;
  float* sc1 = fold + 128, *sh1 = fold + 256;

  hipMemsetAsync(stats, 0, 3072, stream);
  hipMemsetAsync(vcnt, 0, (size_t)4 * NVOX * sizeof(float), stream);
  hipMemsetAsync(vmax, 0, (size_t)NVOX * 64 * sizeof(unsigned int), stream);
  hipMemsetAsync(d_out, 0, (size_t)out_size * sizeof(float), stream);

  voxsum<<<NBLK, TPB, 0, stream>>>(pts, vcnt, vsx, vsy, vsz);
  bn0stats<<<NBLK, TPB, 0, stream>>>(pts, vcnt, vsx, vsy, vsz, W0, s0, q0);
  bnfold<<<1, 64, 0, stream>>>(s0, q0, g0, b0, sc0, sh0, 64);
  pf0max<<<NBLK, TPB, 0, stream>>>(pts, vcnt, vsx, vsy, vsz, W0, sc0, sh0, vmax);
  layer1<1, 0><<<NBLK, TPB, 0, stream>>>(pts, vcnt, vsx, vsy, vsz, W0, sc0, sh0,
                                         vmax, W1, s1, q1, nullptr, nullptr, nullptr);
  layer1<1, 64><<<NBLK, TPB, 0, stream>>>(pts, vcnt, vsx, vsy, vsz, W0, sc0, sh0,
                                          vmax, W1, s1, q1, nullptr, nullptr, nullptr);
  bnfold<<<1, 128, 0, stream>>>(s1, q1, g1, b1, sc1, sh1, 128);
  layer1<0, 0><<<NBLK, TPB, 0, stream>>>(pts, vcnt, vsx, vsy, vsz, W0, sc0, sh0,
                                         vmax, W1, nullptr, nullptr, sc1, sh1,
                                         (unsigned int*)d_out);
  layer1<0, 64><<<NBLK, TPB, 0, stream>>>(pts, vcnt, vsx, vsy, vsz, W0, sc0, sh0,
                                          vmax, W1, nullptr, nullptr, sc1, sh1,
                                          (unsigned int*)d_out);
}